// Round 1
// baseline (1170.383 us; speedup 1.0000x reference)
//
#include <hip/hip_runtime.h>

#define DIN  128
#define DOUT 64

// ---------- helpers ----------
__device__ __forceinline__ unsigned fenc(float f) {
    unsigned u = __float_as_uint(f);
    return (u & 0x80000000u) ? ~u : (u | 0x80000000u);
}
__device__ __forceinline__ float fdec(unsigned u) {
    return (u & 0x80000000u) ? __uint_as_float(u ^ 0x80000000u)
                             : __uint_as_float(~u);
}

// ---------- K1: h0 = x @ W   (fp32, vector ALU; W staged in LDS) ----------
__global__ __launch_bounds__(256) void k_gemm(const float* __restrict__ x,
                                              const float* __restrict__ W,
                                              float* __restrict__ h0, int N) {
    __shared__ float Wl[DIN * DOUT];
    const float4* W4 = (const float4*)W;
    float4* Wl4 = (float4*)Wl;
    for (int i = threadIdx.x; i < DIN * DOUT / 4; i += 256) Wl4[i] = W4[i];
    __syncthreads();

    int wave = threadIdx.x >> 6;
    int lane = threadIdx.x & 63;
    int n = blockIdx.x * 4 + wave;
    if (n >= N) return;

    float xa = x[(size_t)n * DIN + lane];
    float xb = x[(size_t)n * DIN + 64 + lane];
    float acc = 0.f;
#pragma unroll
    for (int k = 0; k < 64; k++)
        acc = fmaf(__shfl(xa, k, 64), Wl[k * DOUT + lane], acc);
#pragma unroll
    for (int k = 0; k < 64; k++)
        acc = fmaf(__shfl(xb, k, 64), Wl[(64 + k) * DOUT + lane], acc);
    h0[(size_t)n * DOUT + lane] = acc;
}

// ---------- K2: in-degree histogram ----------
__global__ __launch_bounds__(256) void k_deg(const int* __restrict__ dst,
                                             unsigned* __restrict__ cnt, int E) {
    int i = blockIdx.x * 256 + threadIdx.x;
    if (i < E) atomicAdd(&cnt[dst[i]], 1u);
}

// ---------- K3: dinv, invdeg ----------
__global__ __launch_bounds__(256) void k_norm(const unsigned* __restrict__ cnt,
                                              float* __restrict__ dinv,
                                              float* __restrict__ invdeg, int N) {
    int n = blockIdx.x * 256 + threadIdx.x;
    if (n < N) {
        float deg = (float)cnt[n] + 1.f;
        dinv[n]   = rsqrtf(deg);
        invdeg[n] = 1.f / deg;
    }
}

// ---------- K4: agg[dst] += norm * h0[src]  (wave per edge) ----------
__global__ __launch_bounds__(256) void k_agg(const int* __restrict__ src,
                                             const int* __restrict__ dst,
                                             const float* __restrict__ dinv,
                                             const float* __restrict__ h0,
                                             float* __restrict__ agg, int E) {
    int tid  = blockIdx.x * 256 + threadIdx.x;
    int eid  = tid >> 6;
    int lane = tid & 63;
    if (eid >= E) return;
    int s = src[eid], d = dst[eid];
    float nrm = dinv[s] * dinv[d];
    float v = h0[(size_t)s * DOUT + lane] * nrm;
    atomicAdd(&agg[(size_t)d * DOUT + lane], v);
}

// ---------- K5: h = agg + h0*invdeg + b   (in place over agg) ----------
__global__ __launch_bounds__(256) void k_combine(float* __restrict__ agg,
                                                 const float* __restrict__ h0,
                                                 const float* __restrict__ invdeg,
                                                 const float* __restrict__ b, int NE) {
    int i = blockIdx.x * 256 + threadIdx.x;
    if (i < NE) {
        int n = i >> 6;
        int d = i & 63;
        agg[i] = agg[i] + h0[i] * invdeg[n] + b[d];
    }
}

// ---------- K6: e[dst] += ||h_d - h_s||^2 ; S[dst] += h_src ----------
__global__ __launch_bounds__(256) void k_energy(const int* __restrict__ src,
                                                const int* __restrict__ dst,
                                                const float* __restrict__ h,
                                                float* __restrict__ e,
                                                float* __restrict__ S, int E) {
    int tid  = blockIdx.x * 256 + threadIdx.x;
    int eid  = tid >> 6;
    int lane = tid & 63;
    if (eid >= E) return;
    int s = src[eid], d = dst[eid];
    float hs = h[(size_t)s * DOUT + lane];
    float hd = h[(size_t)d * DOUT + lane];
    float df = hd - hs;
    float sum = df * df;
#pragma unroll
    for (int off = 32; off > 0; off >>= 1) sum += __shfl_down(sum, off, 64);
    if (lane == 0) atomicAdd(&e[d], sum);
    atomicAdd(&S[(size_t)d * DOUT + lane], hs);
}

// ---------- K7: max of s_n = -e_n/T ----------
__global__ __launch_bounds__(256) void k_max(const float* __restrict__ e,
                                             const float* __restrict__ Tptr,
                                             unsigned* __restrict__ maxenc, int N) {
    float T = *Tptr;
    float m = -3.4e38f;
    for (int i = blockIdx.x * 256 + threadIdx.x; i < N; i += gridDim.x * 256)
        m = fmaxf(m, -e[i] / T);
    __shared__ float sm[256];
    sm[threadIdx.x] = m;
    __syncthreads();
    for (int s = 128; s > 0; s >>= 1) {
        if (threadIdx.x < s) sm[threadIdx.x] = fmaxf(sm[threadIdx.x], sm[threadIdx.x + s]);
        __syncthreads();
    }
    if (threadIdx.x == 0) atomicMax(maxenc, fenc(sm[0]));
}

// ---------- K8: Z = sum exp(t), M = sum exp(t)*t,  t = s - max ----------
__global__ __launch_bounds__(256) void k_sums(const float* __restrict__ e,
                                              const float* __restrict__ Tptr,
                                              const unsigned* __restrict__ maxenc,
                                              float* __restrict__ Zp,
                                              float* __restrict__ Mp, int N) {
    float T = *Tptr;
    float mx = fdec(*maxenc);
    float z = 0.f, mm = 0.f;
    for (int i = blockIdx.x * 256 + threadIdx.x; i < N; i += gridDim.x * 256) {
        float t = -e[i] / T - mx;
        float w = __expf(t);
        z += w;
        mm += w * t;
    }
    __shared__ float sz[256], sM[256];
    sz[threadIdx.x] = z;
    sM[threadIdx.x] = mm;
    __syncthreads();
    for (int s = 128; s > 0; s >>= 1) {
        if (threadIdx.x < s) {
            sz[threadIdx.x] += sz[threadIdx.x + s];
            sM[threadIdx.x] += sM[threadIdx.x + s];
        }
        __syncthreads();
    }
    if (threadIdx.x == 0) {
        atomicAdd(Zp, sz[0]);
        atomicAdd(Mp, sM[0]);
    }
}

// ---------- K9: c_n = p_n * (logp_n + H) ----------
__global__ __launch_bounds__(256) void k_coef(const float* __restrict__ e,
                                              const float* __restrict__ Tptr,
                                              const unsigned* __restrict__ maxenc,
                                              const float* __restrict__ Zp,
                                              const float* __restrict__ Mp,
                                              float* __restrict__ c, int N) {
    int n = blockIdx.x * 256 + threadIdx.x;
    if (n >= N) return;
    float T = *Tptr;
    float mx = fdec(*maxenc);
    float Z = *Zp, M = *Mp;
    float logZ = logf(Z);
    float H = logZ - M / Z;
    float t = -e[n] / T - mx;
    float lp = t - logZ;
    c[n] = expf(lp) * (lp + H);
}

// ---------- K10: A[src] += c_dst ; B[src] += c_dst * h_dst ----------
__global__ __launch_bounds__(256) void k_grad(const int* __restrict__ src,
                                              const int* __restrict__ dst,
                                              const float* __restrict__ c,
                                              const float* __restrict__ h,
                                              float* __restrict__ A,
                                              float* __restrict__ B, int E) {
    int tid  = blockIdx.x * 256 + threadIdx.x;
    int eid  = tid >> 6;
    int lane = tid & 63;
    if (eid >= E) return;
    int s = src[eid], d = dst[eid];
    float cd = c[d];
    float hd = h[(size_t)d * DOUT + lane];
    atomicAdd(&B[(size_t)s * DOUT + lane], cd * hd);
    if (lane == 0) atomicAdd(&A[s], cd);
}

// ---------- K11: out = h + w*(2c(cnt*h - S) + 2(A*h - B)) ----------
__global__ __launch_bounds__(256) void k_final(const float* __restrict__ h,
                                               const float* __restrict__ c,
                                               const unsigned* __restrict__ cnt,
                                               const float* __restrict__ S,
                                               const float* __restrict__ A,
                                               const float* __restrict__ B,
                                               const float* __restrict__ wptr,
                                               float* __restrict__ out, int NE) {
    int i = blockIdx.x * 256 + threadIdx.x;
    if (i >= NE) return;
    int n = i >> 6;
    float hh = h[i];
    float w = *wptr;
    float g = 2.f * c[n] * ((float)cnt[n] * hh - S[i]) + 2.f * (A[n] * hh - B[i]);
    out[i] = hh + w * g;
}

extern "C" void kernel_launch(void* const* d_in, const int* in_sizes, int n_in,
                              void* d_out, int out_size, void* d_ws, size_t ws_size,
                              hipStream_t stream) {
    const float* x    = (const float*)d_in[0];
    const int*   ei   = (const int*)d_in[1];
    const float* wptr = (const float*)d_in[2];
    const float* Tptr = (const float*)d_in[3];
    const float* W    = (const float*)d_in[4];
    const float* b    = (const float*)d_in[5];
    float* out = (float*)d_out;

    const int N = in_sizes[0] / DIN;   // 100000
    const int E = in_sizes[1] / 2;     // 1000000
    const int NE = N * DOUT;           // 6.4M
    const int* src = ei;
    const int* dst = ei + E;

    // workspace layout (floats)
    float* P1 = (float*)d_ws;          // h0, later S
    float* P2 = P1 + NE;               // agg, later h
    float* P3 = P2 + NE;               // B
    unsigned* cnt = (unsigned*)(P3 + NE);
    float* e      = (float*)(cnt + N);
    float* A      = e + N;
    float* c      = A + N;
    float* dinv   = c + N;
    float* invdeg = dinv + N;
    unsigned* maxenc = (unsigned*)(invdeg + N);
    float* Zp = (float*)(maxenc + 1);
    float* Mp = Zp + 1;

    // zero what needs zeroing (ws is poisoned 0xAA before every call)
    hipMemsetAsync(P2, 0, (size_t)NE * 4, stream);           // agg
    hipMemsetAsync(P3, 0, (size_t)NE * 4, stream);           // B
    hipMemsetAsync(cnt, 0, (size_t)N * 4, stream);
    hipMemsetAsync(e,   0, (size_t)N * 4, stream);
    hipMemsetAsync(A,   0, (size_t)N * 4, stream);
    hipMemsetAsync(maxenc, 0, 12, stream);                   // maxenc, Z, M

    const int edgeBlocks = (E * 64 + 255) / 256;             // wave per edge
    const int nodeBlocks = (N + 255) / 256;
    const int neBlocks   = (NE + 255) / 256;

    k_gemm<<<(N + 3) / 4, 256, 0, stream>>>(x, W, P1, N);
    k_deg<<<(E + 255) / 256, 256, 0, stream>>>(dst, cnt, E);
    k_norm<<<nodeBlocks, 256, 0, stream>>>(cnt, dinv, invdeg, N);
    k_agg<<<edgeBlocks, 256, 0, stream>>>(src, dst, dinv, P1, P2, E);
    k_combine<<<neBlocks, 256, 0, stream>>>(P2, P1, invdeg, b, NE);

    // P1 (h0) is dead now; reuse as S
    hipMemsetAsync(P1, 0, (size_t)NE * 4, stream);
    k_energy<<<edgeBlocks, 256, 0, stream>>>(src, dst, P2, e, P1, E);
    k_max<<<1024, 256, 0, stream>>>(e, Tptr, maxenc, N);
    k_sums<<<1024, 256, 0, stream>>>(e, Tptr, maxenc, Zp, Mp, N);
    k_coef<<<nodeBlocks, 256, 0, stream>>>(e, Tptr, maxenc, Zp, Mp, c, N);
    k_grad<<<edgeBlocks, 256, 0, stream>>>(src, dst, c, P2, A, P3, E);
    k_final<<<neBlocks, 256, 0, stream>>>(P2, c, cnt, P1, A, P3, wptr, out, NE);
}

// Round 2
// 755.411 us; speedup vs baseline: 1.5493x; 1.5493x over previous
//
#include <hip/hip_runtime.h>

#define DIN  128
#define DOUT 64

// ---------- helpers ----------
__device__ __forceinline__ unsigned fenc(float f) {
    unsigned u = __float_as_uint(f);
    return (u & 0x80000000u) ? ~u : (u | 0x80000000u);
}
__device__ __forceinline__ float fdec(unsigned u) {
    return (u & 0x80000000u) ? __uint_as_float(u ^ 0x80000000u)
                             : __uint_as_float(~u);
}

// ---------- K1: histogram in-degree (cnt[0..N)) and out-degree (cnt[N..2N)) ----------
__global__ __launch_bounds__(256) void k_hist(const int* __restrict__ src,
                                              const int* __restrict__ dst,
                                              unsigned* __restrict__ cnt,
                                              int N, int E) {
    int i = blockIdx.x * 256 + threadIdx.x;
    if (i < E) {
        atomicAdd(&cnt[dst[i]], 1u);
        atomicAdd(&cnt[N + src[i]], 1u);
    }
}

// ---------- K2: per-block reduce for scan ----------
__global__ __launch_bounds__(256) void k_scan1(const unsigned* __restrict__ cnt,
                                               unsigned* __restrict__ bsums, int n2) {
    __shared__ unsigned s[256];
    int i = blockIdx.x * 256 + threadIdx.x;
    s[threadIdx.x] = (i < n2) ? cnt[i] : 0u;
    __syncthreads();
    for (int st = 128; st > 0; st >>= 1) {
        if (threadIdx.x < st) s[threadIdx.x] += s[threadIdx.x + st];
        __syncthreads();
    }
    if (threadIdx.x == 0) bsums[blockIdx.x] = s[0];
}

// ---------- K3: single-block exclusive scan of block sums (NB <= 1024) ----------
__global__ __launch_bounds__(1024) void k_scan2(unsigned* __restrict__ bsums, int NB) {
    __shared__ unsigned s[1024];
    int tid = threadIdx.x;
    unsigned v = (tid < NB) ? bsums[tid] : 0u;
    s[tid] = v;
    __syncthreads();
    for (int st = 1; st < 1024; st <<= 1) {
        unsigned t = (tid >= st) ? s[tid - st] : 0u;
        __syncthreads();
        s[tid] += t;
        __syncthreads();
    }
    if (tid < NB) bsums[tid] = s[tid] - v;   // exclusive
}

// ---------- K4: block scan + add base -> off, cur; also dinv ----------
__global__ __launch_bounds__(256) void k_scan3(const unsigned* __restrict__ cnt,
                                               const unsigned* __restrict__ bsums,
                                               unsigned* __restrict__ off,
                                               unsigned* __restrict__ cur,
                                               float* __restrict__ dinv,
                                               int N, int n2, unsigned total) {
    __shared__ unsigned s[256];
    int i = blockIdx.x * 256 + threadIdx.x;
    unsigned v = (i < n2) ? cnt[i] : 0u;
    s[threadIdx.x] = v;
    __syncthreads();
    for (int st = 1; st < 256; st <<= 1) {
        unsigned t = (threadIdx.x >= st) ? s[threadIdx.x - st] : 0u;
        __syncthreads();
        s[threadIdx.x] += t;
        __syncthreads();
    }
    unsigned excl = s[threadIdx.x] - v + bsums[blockIdx.x];
    if (i < n2) {
        off[i] = excl;
        cur[i] = excl;
        if (i < N) dinv[i] = rsqrtf((float)v + 1.f);
    }
    if (i == 0) off[n2] = total;
}

// ---------- K5: scatter edge payloads into both CSRs ----------
__global__ __launch_bounds__(256) void k_scatter(const int* __restrict__ src,
                                                 const int* __restrict__ dst,
                                                 unsigned* __restrict__ cur,
                                                 int* __restrict__ pay,
                                                 int N, int E) {
    int i = blockIdx.x * 256 + threadIdx.x;
    if (i < E) {
        int s = src[i], d = dst[i];
        unsigned p1 = atomicAdd(&cur[d], 1u);
        pay[p1] = s;                       // in-CSR stores src id
        unsigned p2 = atomicAdd(&cur[N + s], 1u);
        pay[p2] = d;                       // out-CSR stores dst id
    }
}

// ---------- K6: h0s = dinv[n] * (x[n] @ W)  (fp32 vector ALU, W in LDS) ----------
__global__ __launch_bounds__(256) void k_gemm(const float* __restrict__ x,
                                              const float* __restrict__ W,
                                              const float* __restrict__ dinv,
                                              float* __restrict__ h0s, int N) {
    __shared__ float Wl[DIN * DOUT];
    const float4* W4 = (const float4*)W;
    float4* Wl4 = (float4*)Wl;
    for (int i = threadIdx.x; i < DIN * DOUT / 4; i += 256) Wl4[i] = W4[i];
    __syncthreads();

    int wave = threadIdx.x >> 6;
    int lane = threadIdx.x & 63;
    int n = blockIdx.x * 4 + wave;
    if (n >= N) return;

    float xa = x[(size_t)n * DIN + lane];
    float xb = x[(size_t)n * DIN + 64 + lane];
    float acc = 0.f;
#pragma unroll
    for (int k = 0; k < 64; k++)
        acc = fmaf(__shfl(xa, k, 64), Wl[k * DOUT + lane], acc);
#pragma unroll
    for (int k = 0; k < 64; k++)
        acc = fmaf(__shfl(xb, k, 64), Wl[(64 + k) * DOUT + lane], acc);
    h0s[(size_t)n * DOUT + lane] = acc * dinv[n];
}

// ---------- K7: gather agg + fused combine:  h[n] = dinv[n]*(sum h0s[src] + h0s[n]) + b ----------
__global__ __launch_bounds__(256) void k_agg(const unsigned* __restrict__ off,
                                             const int* __restrict__ pay,
                                             const float* __restrict__ dinv,
                                             const float* __restrict__ h0s,
                                             const float* __restrict__ b,
                                             float* __restrict__ h, int N) {
    int wave = threadIdx.x >> 6;
    int lane = threadIdx.x & 63;
    int n = blockIdx.x * 4 + wave;
    if (n >= N) return;
    int beg = off[n], end = off[n + 1];
    float acc = 0.f;
    int i = beg;
    for (; i + 2 <= end; i += 2) {
        int s0 = pay[i], s1 = pay[i + 1];
        float a0 = h0s[(size_t)s0 * DOUT + lane];
        float a1 = h0s[(size_t)s1 * DOUT + lane];
        acc += a0 + a1;
    }
    if (i < end) acc += h0s[(size_t)pay[i] * DOUT + lane];
    h[(size_t)n * DOUT + lane] = dinv[n] * (acc + h0s[(size_t)n * DOUT + lane]) + b[lane];
}

// ---------- K8: gather energy + S:  e[n] = sum||h_n - h_s||^2, S[n] = sum h_s ----------
__global__ __launch_bounds__(256) void k_energy(const unsigned* __restrict__ off,
                                                const int* __restrict__ pay,
                                                const float* __restrict__ h,
                                                float* __restrict__ e,
                                                float* __restrict__ S, int N) {
    int wave = threadIdx.x >> 6;
    int lane = threadIdx.x & 63;
    int n = blockIdx.x * 4 + wave;
    if (n >= N) return;
    int beg = off[n], end = off[n + 1];
    float hm = h[(size_t)n * DOUT + lane];
    float Ssum = 0.f, esum = 0.f;
    int i = beg;
    for (; i + 2 <= end; i += 2) {
        int s0 = pay[i], s1 = pay[i + 1];
        float h0v = h[(size_t)s0 * DOUT + lane];
        float h1v = h[(size_t)s1 * DOUT + lane];
        Ssum += h0v + h1v;
        float d0 = hm - h0v, d1 = hm - h1v;
        esum += d0 * d0 + d1 * d1;
    }
    if (i < end) {
        float hv = h[(size_t)pay[i] * DOUT + lane];
        Ssum += hv;
        float d = hm - hv;
        esum += d * d;
    }
#pragma unroll
    for (int o = 32; o > 0; o >>= 1) esum += __shfl_down(esum, o, 64);
    if (lane == 0) e[n] = esum;
    S[(size_t)n * DOUT + lane] = Ssum;
}

// ---------- K9: max of s_n = -e_n/T ----------
__global__ __launch_bounds__(256) void k_max(const float* __restrict__ e,
                                             const float* __restrict__ Tptr,
                                             unsigned* __restrict__ maxenc, int N) {
    float T = *Tptr;
    float m = -3.4e38f;
    for (int i = blockIdx.x * 256 + threadIdx.x; i < N; i += gridDim.x * 256)
        m = fmaxf(m, -e[i] / T);
    __shared__ float sm[256];
    sm[threadIdx.x] = m;
    __syncthreads();
    for (int s = 128; s > 0; s >>= 1) {
        if (threadIdx.x < s) sm[threadIdx.x] = fmaxf(sm[threadIdx.x], sm[threadIdx.x + s]);
        __syncthreads();
    }
    if (threadIdx.x == 0) atomicMax(maxenc, fenc(sm[0]));
}

// ---------- K10: Z = sum exp(t), M = sum exp(t)*t ----------
__global__ __launch_bounds__(256) void k_sums(const float* __restrict__ e,
                                              const float* __restrict__ Tptr,
                                              const unsigned* __restrict__ maxenc,
                                              float* __restrict__ Zp,
                                              float* __restrict__ Mp, int N) {
    float T = *Tptr;
    float mx = fdec(*maxenc);
    float z = 0.f, mm = 0.f;
    for (int i = blockIdx.x * 256 + threadIdx.x; i < N; i += gridDim.x * 256) {
        float t = -e[i] / T - mx;
        float w = __expf(t);
        z += w;
        mm += w * t;
    }
    __shared__ float sz[256], sM[256];
    sz[threadIdx.x] = z;
    sM[threadIdx.x] = mm;
    __syncthreads();
    for (int s = 128; s > 0; s >>= 1) {
        if (threadIdx.x < s) {
            sz[threadIdx.x] += sz[threadIdx.x + s];
            sM[threadIdx.x] += sM[threadIdx.x + s];
        }
        __syncthreads();
    }
    if (threadIdx.x == 0) {
        atomicAdd(Zp, sz[0]);
        atomicAdd(Mp, sM[0]);
    }
}

// ---------- K11: c_n = p_n * (logp_n + H) ----------
__global__ __launch_bounds__(256) void k_coef(const float* __restrict__ e,
                                              const float* __restrict__ Tptr,
                                              const unsigned* __restrict__ maxenc,
                                              const float* __restrict__ Zp,
                                              const float* __restrict__ Mp,
                                              float* __restrict__ c, int N) {
    int n = blockIdx.x * 256 + threadIdx.x;
    if (n >= N) return;
    float T = *Tptr;
    float mx = fdec(*maxenc);
    float Z = *Zp, M = *Mp;
    float logZ = logf(Z);
    float H = logZ - M / Z;
    float t = -e[n] / T - mx;
    float lp = t - logZ;
    c[n] = expf(lp) * (lp + H);
}

// ---------- K12: out-CSR gather of A,B + fused final ----------
// A_n = sum_{n->d} c_d ; B_n = sum_{n->d} c_d*h_d
// out = h + w*(2*c_n*(cnt_n*h - S) + 2*(A*h - B))
__global__ __launch_bounds__(256) void k_grad_final(const unsigned* __restrict__ off,
                                                    const int* __restrict__ pay,
                                                    const float* __restrict__ c,
                                                    const float* __restrict__ h,
                                                    const float* __restrict__ S,
                                                    const unsigned* __restrict__ cnt,
                                                    const float* __restrict__ wptr,
                                                    float* __restrict__ out, int N) {
    int wave = threadIdx.x >> 6;
    int lane = threadIdx.x & 63;
    int n = blockIdx.x * 4 + wave;
    if (n >= N) return;
    int beg = off[N + n], end = off[N + n + 1];
    float A = 0.f, B = 0.f;
    int i = beg;
    for (; i + 2 <= end; i += 2) {
        int d0 = pay[i], d1 = pay[i + 1];
        float c0 = c[d0], c1 = c[d1];
        B += c0 * h[(size_t)d0 * DOUT + lane] + c1 * h[(size_t)d1 * DOUT + lane];
        A += c0 + c1;
    }
    if (i < end) {
        int d = pay[i];
        float cd = c[d];
        B += cd * h[(size_t)d * DOUT + lane];
        A += cd;
    }
    size_t idx = (size_t)n * DOUT + lane;
    float hm = h[idx];
    float w = *wptr;
    float g = 2.f * c[n] * ((float)cnt[n] * hm - S[idx]) + 2.f * (A * hm - B);
    out[idx] = hm + w * g;
}

extern "C" void kernel_launch(void* const* d_in, const int* in_sizes, int n_in,
                              void* d_out, int out_size, void* d_ws, size_t ws_size,
                              hipStream_t stream) {
    const float* x    = (const float*)d_in[0];
    const int*   ei   = (const int*)d_in[1];
    const float* wptr = (const float*)d_in[2];
    const float* Tptr = (const float*)d_in[3];
    const float* W    = (const float*)d_in[4];
    const float* b    = (const float*)d_in[5];
    float* out = (float*)d_out;

    const int N  = in_sizes[0] / DIN;   // 100000
    const int E  = in_sizes[1] / 2;     // 1000000
    const int NE = N * DOUT;
    const int n2 = 2 * N;
    const int NB = (n2 + 255) / 256;    // 782 <= 1024
    const int* src = ei;
    const int* dst = ei + E;

    // workspace layout
    float*    h0s  = (float*)d_ws;                 // NE (reused as S later)
    float*    h    = h0s + NE;                     // NE
    int*      pay  = (int*)(h + NE);               // 2E
    unsigned* cnt  = (unsigned*)(pay + 2 * (size_t)E);  // 2N
    unsigned* off  = cnt + n2;                     // 2N+1
    unsigned* cur  = off + n2 + 1;                 // 2N
    unsigned* bsum = cur + n2;                     // NB (<=1024)
    float*    e    = (float*)(bsum + 1024);        // N
    float*    c    = e + N;                        // N
    float*    dinv = c + N;                        // N
    unsigned* maxenc = (unsigned*)(dinv + N);      // 1
    float*    Zp   = (float*)(maxenc + 1);         // 1
    float*    Mp   = Zp + 1;                       // 1
    float*    S    = h0s;                          // reuse after k_agg

    hipMemsetAsync(cnt, 0, (size_t)n2 * 4, stream);
    hipMemsetAsync(maxenc, 0, 12, stream);

    const int nodeW = (N + 3) / 4;                 // wave-per-node grids
    const int nodeBlocks = (N + 255) / 256;
    const int edgeBlocks = (E + 255) / 256;

    k_hist<<<edgeBlocks, 256, 0, stream>>>(src, dst, cnt, N, E);
    k_scan1<<<NB, 256, 0, stream>>>(cnt, bsum, n2);
    k_scan2<<<1, 1024, 0, stream>>>(bsum, NB);
    k_scan3<<<NB, 256, 0, stream>>>(cnt, bsum, off, cur, dinv, N, n2, (unsigned)(2 * E));
    k_scatter<<<edgeBlocks, 256, 0, stream>>>(src, dst, cur, pay, N, E);
    k_gemm<<<(N + 3) / 4, 256, 0, stream>>>(x, W, dinv, h0s, N);
    k_agg<<<nodeW, 256, 0, stream>>>(off, pay, dinv, h0s, b, h, N);
    k_energy<<<nodeW, 256, 0, stream>>>(off, pay, h, e, S, N);
    k_max<<<400, 256, 0, stream>>>(e, Tptr, maxenc, N);
    k_sums<<<400, 256, 0, stream>>>(e, Tptr, maxenc, Zp, Mp, N);
    k_coef<<<nodeBlocks, 256, 0, stream>>>(e, Tptr, maxenc, Zp, Mp, c, N);
    k_grad_final<<<nodeW, 256, 0, stream>>>(off, pay, c, h, S, cnt, wptr, out, N);
}

// Round 3
// 600.262 us; speedup vs baseline: 1.9498x; 1.2585x over previous
//
#include <hip/hip_runtime.h>

#define DIN  128
#define DOUT 64
#define TN   64    // nodes per gemm block
#define XP   132   // padded X-tile row (floats), %4==0, breaks 128-stride banking

// ---------- helpers ----------
__device__ __forceinline__ unsigned fenc(float f) {
    unsigned u = __float_as_uint(f);
    return (u & 0x80000000u) ? ~u : (u | 0x80000000u);
}
__device__ __forceinline__ float fdec(unsigned u) {
    return (u & 0x80000000u) ? __uint_as_float(u ^ 0x80000000u)
                             : __uint_as_float(~u);
}

// ---------- K1: histogram in-degree (cnt[0..N)) and out-degree (cnt[N..2N)) ----------
__global__ __launch_bounds__(256) void k_hist(const int* __restrict__ src,
                                              const int* __restrict__ dst,
                                              unsigned* __restrict__ cnt,
                                              int N, int E) {
    int i = blockIdx.x * 256 + threadIdx.x;
    if (i < E) {
        atomicAdd(&cnt[dst[i]], 1u);
        atomicAdd(&cnt[N + src[i]], 1u);
    }
}

// ---------- K2: per-block reduce for scan ----------
__global__ __launch_bounds__(256) void k_scan1(const unsigned* __restrict__ cnt,
                                               unsigned* __restrict__ bsums, int n2) {
    __shared__ unsigned s[256];
    int i = blockIdx.x * 256 + threadIdx.x;
    s[threadIdx.x] = (i < n2) ? cnt[i] : 0u;
    __syncthreads();
    for (int st = 128; st > 0; st >>= 1) {
        if (threadIdx.x < st) s[threadIdx.x] += s[threadIdx.x + st];
        __syncthreads();
    }
    if (threadIdx.x == 0) bsums[blockIdx.x] = s[0];
}

// ---------- K3: single-block exclusive scan of block sums (NB <= 1024) ----------
__global__ __launch_bounds__(1024) void k_scan2(unsigned* __restrict__ bsums, int NB) {
    __shared__ unsigned s[1024];
    int tid = threadIdx.x;
    unsigned v = (tid < NB) ? bsums[tid] : 0u;
    s[tid] = v;
    __syncthreads();
    for (int st = 1; st < 1024; st <<= 1) {
        unsigned t = (tid >= st) ? s[tid - st] : 0u;
        __syncthreads();
        s[tid] += t;
        __syncthreads();
    }
    if (tid < NB) bsums[tid] = s[tid] - v;   // exclusive
}

// ---------- K4: block scan + add base -> off, cur; also dinv ----------
__global__ __launch_bounds__(256) void k_scan3(const unsigned* __restrict__ cnt,
                                               const unsigned* __restrict__ bsums,
                                               unsigned* __restrict__ off,
                                               unsigned* __restrict__ cur,
                                               float* __restrict__ dinv,
                                               int N, int n2, unsigned total) {
    __shared__ unsigned s[256];
    int i = blockIdx.x * 256 + threadIdx.x;
    unsigned v = (i < n2) ? cnt[i] : 0u;
    s[threadIdx.x] = v;
    __syncthreads();
    for (int st = 1; st < 256; st <<= 1) {
        unsigned t = (threadIdx.x >= st) ? s[threadIdx.x - st] : 0u;
        __syncthreads();
        s[threadIdx.x] += t;
        __syncthreads();
    }
    unsigned excl = s[threadIdx.x] - v + bsums[blockIdx.x];
    if (i < n2) {
        off[i] = excl;
        cur[i] = excl;
        if (i < N) dinv[i] = rsqrtf((float)v + 1.f);
    }
    if (i == 0) off[n2] = total;
}

// ---------- K5: scatter edge payloads into both CSRs ----------
__global__ __launch_bounds__(256) void k_scatter(const int* __restrict__ src,
                                                 const int* __restrict__ dst,
                                                 unsigned* __restrict__ cur,
                                                 int* __restrict__ pay,
                                                 int N, int E) {
    int i = blockIdx.x * 256 + threadIdx.x;
    if (i < E) {
        int s = src[i], d = dst[i];
        unsigned p1 = atomicAdd(&cur[d], 1u);
        pay[p1] = s;                       // in-CSR stores src id
        unsigned p2 = atomicAdd(&cur[N + s], 1u);
        pay[p2] = d;                       // out-CSR stores dst id
    }
}

// ---------- K6: h0s = dinv[n] * (x[n] @ W)  register-blocked 4x4 tile GEMM ----------
__global__ __launch_bounds__(256) void k_gemm(const float* __restrict__ x,
                                              const float* __restrict__ W,
                                              const float* __restrict__ dinv,
                                              float* __restrict__ h0s, int N) {
    __shared__ float Xs[TN * XP];        // 33792 B
    __shared__ float Ws[DIN * DOUT];     // 32768 B

    // stage W (8192 floats = 2048 float4)
    for (int i = threadIdx.x; i < DIN * DOUT / 4; i += 256)
        ((float4*)Ws)[i] = ((const float4*)W)[i];

    // stage X tile: 64 rows x 128 floats (32 float4 per row)
    int base = blockIdx.x * TN;
    int kq = threadIdx.x & 31;           // float4 index along row
    int rr = threadIdx.x >> 5;           // 8 rows per pass
#pragma unroll
    for (int it = 0; it < 8; ++it) {
        int r = rr + it * 8;
        int n = base + r;
        float4 v = make_float4(0.f, 0.f, 0.f, 0.f);
        if (n < N) v = ((const float4*)(x + (size_t)n * DIN))[kq];
        *((float4*)(Xs + r * XP + 4 * kq)) = v;
    }
    __syncthreads();

    int tx = threadIdx.x & 15;           // col group: cols 4*tx..4*tx+3
    int ty = threadIdx.x >> 4;           // row group: rows 4*ty..4*ty+3
    float acc[4][4] = {};

#pragma unroll 4
    for (int k = 0; k < DIN; k += 4) {
        float4 a0 = *((float4*)(Xs + (4 * ty + 0) * XP + k));
        float4 a1 = *((float4*)(Xs + (4 * ty + 1) * XP + k));
        float4 a2 = *((float4*)(Xs + (4 * ty + 2) * XP + k));
        float4 a3 = *((float4*)(Xs + (4 * ty + 3) * XP + k));
        float4 w0 = *((float4*)(Ws + (k + 0) * DOUT + 4 * tx));
        float4 w1 = *((float4*)(Ws + (k + 1) * DOUT + 4 * tx));
        float4 w2 = *((float4*)(Ws + (k + 2) * DOUT + 4 * tx));
        float4 w3 = *((float4*)(Ws + (k + 3) * DOUT + 4 * tx));
#define ROW(j, aj)                                                             \
        acc[j][0] = fmaf(aj.x, w0.x, fmaf(aj.y, w1.x, fmaf(aj.z, w2.x, fmaf(aj.w, w3.x, acc[j][0])))); \
        acc[j][1] = fmaf(aj.x, w0.y, fmaf(aj.y, w1.y, fmaf(aj.z, w2.y, fmaf(aj.w, w3.y, acc[j][1])))); \
        acc[j][2] = fmaf(aj.x, w0.z, fmaf(aj.y, w1.z, fmaf(aj.z, w2.z, fmaf(aj.w, w3.z, acc[j][2])))); \
        acc[j][3] = fmaf(aj.x, w0.w, fmaf(aj.y, w1.w, fmaf(aj.z, w2.w, fmaf(aj.w, w3.w, acc[j][3]))));
        ROW(0, a0) ROW(1, a1) ROW(2, a2) ROW(3, a3)
#undef ROW
    }

#pragma unroll
    for (int j = 0; j < 4; ++j) {
        int n = base + 4 * ty + j;
        if (n < N) {
            float dv = dinv[n];
            float4 o = make_float4(acc[j][0] * dv, acc[j][1] * dv,
                                   acc[j][2] * dv, acc[j][3] * dv);
            *((float4*)(h0s + (size_t)n * DOUT + 4 * tx)) = o;
        }
    }
}

// ---------- K7: gather agg + fused combine:  h[n] = dinv[n]*(sum h0s[src] + h0s[n]) + b ----------
__global__ __launch_bounds__(256) void k_agg(const unsigned* __restrict__ off,
                                             const int* __restrict__ pay,
                                             const float* __restrict__ dinv,
                                             const float* __restrict__ h0s,
                                             const float* __restrict__ b,
                                             float* __restrict__ h, int N) {
    int wave = threadIdx.x >> 6;
    int lane = threadIdx.x & 63;
    int n = blockIdx.x * 4 + wave;
    if (n >= N) return;
    int beg = off[n], end = off[n + 1];
    float acc = 0.f;
    int i = beg;
    for (; i + 2 <= end; i += 2) {
        int s0 = pay[i], s1 = pay[i + 1];
        float a0 = h0s[(size_t)s0 * DOUT + lane];
        float a1 = h0s[(size_t)s1 * DOUT + lane];
        acc += a0 + a1;
    }
    if (i < end) acc += h0s[(size_t)pay[i] * DOUT + lane];
    h[(size_t)n * DOUT + lane] = dinv[n] * (acc + h0s[(size_t)n * DOUT + lane]) + b[lane];
}

// ---------- K8: gather energy + S:  e[n] = sum||h_n - h_s||^2, S[n] = sum h_s ----------
__global__ __launch_bounds__(256) void k_energy(const unsigned* __restrict__ off,
                                                const int* __restrict__ pay,
                                                const float* __restrict__ h,
                                                float* __restrict__ e,
                                                float* __restrict__ S, int N) {
    int wave = threadIdx.x >> 6;
    int lane = threadIdx.x & 63;
    int n = blockIdx.x * 4 + wave;
    if (n >= N) return;
    int beg = off[n], end = off[n + 1];
    float hm = h[(size_t)n * DOUT + lane];
    float Ssum = 0.f, esum = 0.f;
    int i = beg;
    for (; i + 2 <= end; i += 2) {
        int s0 = pay[i], s1 = pay[i + 1];
        float h0v = h[(size_t)s0 * DOUT + lane];
        float h1v = h[(size_t)s1 * DOUT + lane];
        Ssum += h0v + h1v;
        float d0 = hm - h0v, d1 = hm - h1v;
        esum += d0 * d0 + d1 * d1;
    }
    if (i < end) {
        float hv = h[(size_t)pay[i] * DOUT + lane];
        Ssum += hv;
        float d = hm - hv;
        esum += d * d;
    }
#pragma unroll
    for (int o = 32; o > 0; o >>= 1) esum += __shfl_down(esum, o, 64);
    if (lane == 0) e[n] = esum;
    S[(size_t)n * DOUT + lane] = Ssum;
}

// ---------- K9: max of s_n = -e_n/T ----------
__global__ __launch_bounds__(256) void k_max(const float* __restrict__ e,
                                             const float* __restrict__ Tptr,
                                             unsigned* __restrict__ maxenc, int N) {
    float T = *Tptr;
    float m = -3.4e38f;
    for (int i = blockIdx.x * 256 + threadIdx.x; i < N; i += gridDim.x * 256)
        m = fmaxf(m, -e[i] / T);
    __shared__ float sm[256];
    sm[threadIdx.x] = m;
    __syncthreads();
    for (int s = 128; s > 0; s >>= 1) {
        if (threadIdx.x < s) sm[threadIdx.x] = fmaxf(sm[threadIdx.x], sm[threadIdx.x + s]);
        __syncthreads();
    }
    if (threadIdx.x == 0) atomicMax(maxenc, fenc(sm[0]));
}

// ---------- K10: Z = sum exp(t), M = sum exp(t)*t ----------
__global__ __launch_bounds__(256) void k_sums(const float* __restrict__ e,
                                              const float* __restrict__ Tptr,
                                              const unsigned* __restrict__ maxenc,
                                              float* __restrict__ Zp,
                                              float* __restrict__ Mp, int N) {
    float T = *Tptr;
    float mx = fdec(*maxenc);
    float z = 0.f, mm = 0.f;
    for (int i = blockIdx.x * 256 + threadIdx.x; i < N; i += gridDim.x * 256) {
        float t = -e[i] / T - mx;
        float w = __expf(t);
        z += w;
        mm += w * t;
    }
    __shared__ float sz[256], sM[256];
    sz[threadIdx.x] = z;
    sM[threadIdx.x] = mm;
    __syncthreads();
    for (int s = 128; s > 0; s >>= 1) {
        if (threadIdx.x < s) {
            sz[threadIdx.x] += sz[threadIdx.x + s];
            sM[threadIdx.x] += sM[threadIdx.x + s];
        }
        __syncthreads();
    }
    if (threadIdx.x == 0) {
        atomicAdd(Zp, sz[0]);
        atomicAdd(Mp, sM[0]);
    }
}

// ---------- K11: c_n = p_n * (logp_n + H) ----------
__global__ __launch_bounds__(256) void k_coef(const float* __restrict__ e,
                                              const float* __restrict__ Tptr,
                                              const unsigned* __restrict__ maxenc,
                                              const float* __restrict__ Zp,
                                              const float* __restrict__ Mp,
                                              float* __restrict__ c, int N) {
    int n = blockIdx.x * 256 + threadIdx.x;
    if (n >= N) return;
    float T = *Tptr;
    float mx = fdec(*maxenc);
    float Z = *Zp, M = *Mp;
    float logZ = logf(Z);
    float H = logZ - M / Z;
    float t = -e[n] / T - mx;
    float lp = t - logZ;
    c[n] = expf(lp) * (lp + H);
}

// ---------- K12: out-CSR gather of A,B + fused final ----------
__global__ __launch_bounds__(256) void k_grad_final(const unsigned* __restrict__ off,
                                                    const int* __restrict__ pay,
                                                    const float* __restrict__ c,
                                                    const float* __restrict__ h,
                                                    const float* __restrict__ S,
                                                    const unsigned* __restrict__ cnt,
                                                    const float* __restrict__ wptr,
                                                    float* __restrict__ out, int N) {
    int wave = threadIdx.x >> 6;
    int lane = threadIdx.x & 63;
    int n = blockIdx.x * 4 + wave;
    if (n >= N) return;
    int beg = off[N + n], end = off[N + n + 1];
    float A = 0.f, B = 0.f;
    int i = beg;
    for (; i + 2 <= end; i += 2) {
        int d0 = pay[i], d1 = pay[i + 1];
        float c0 = c[d0], c1 = c[d1];
        B += c0 * h[(size_t)d0 * DOUT + lane] + c1 * h[(size_t)d1 * DOUT + lane];
        A += c0 + c1;
    }
    if (i < end) {
        int d = pay[i];
        float cd = c[d];
        B += cd * h[(size_t)d * DOUT + lane];
        A += cd;
    }
    size_t idx = (size_t)n * DOUT + lane;
    float hm = h[idx];
    float w = *wptr;
    float g = 2.f * c[n] * ((float)cnt[n] * hm - S[idx]) + 2.f * (A * hm - B);
    out[idx] = hm + w * g;
}

extern "C" void kernel_launch(void* const* d_in, const int* in_sizes, int n_in,
                              void* d_out, int out_size, void* d_ws, size_t ws_size,
                              hipStream_t stream) {
    const float* x    = (const float*)d_in[0];
    const int*   ei   = (const int*)d_in[1];
    const float* wptr = (const float*)d_in[2];
    const float* Tptr = (const float*)d_in[3];
    const float* W    = (const float*)d_in[4];
    const float* b    = (const float*)d_in[5];
    float* out = (float*)d_out;

    const int N  = in_sizes[0] / DIN;   // 100000
    const int E  = in_sizes[1] / 2;     // 1000000
    const int NE = N * DOUT;
    const int n2 = 2 * N;
    const int NB = (n2 + 255) / 256;    // 782 <= 1024
    const int* src = ei;
    const int* dst = ei + E;

    // workspace layout
    float*    h0s  = (float*)d_ws;                 // NE (reused as S later)
    float*    h    = h0s + NE;                     // NE
    int*      pay  = (int*)(h + NE);               // 2E
    unsigned* cnt  = (unsigned*)(pay + 2 * (size_t)E);  // 2N
    unsigned* off  = cnt + n2;                     // 2N+1
    unsigned* cur  = off + n2 + 1;                 // 2N
    unsigned* bsum = cur + n2;                     // NB (<=1024)
    float*    e    = (float*)(bsum + 1024);        // N
    float*    c    = e + N;                        // N
    float*    dinv = c + N;                        // N
    unsigned* maxenc = (unsigned*)(dinv + N);      // 1
    float*    Zp   = (float*)(maxenc + 1);         // 1
    float*    Mp   = Zp + 1;                       // 1
    float*    S    = h0s;                          // reuse after k_agg

    hipMemsetAsync(cnt, 0, (size_t)n2 * 4, stream);
    hipMemsetAsync(maxenc, 0, 12, stream);

    const int nodeW = (N + 3) / 4;                 // wave-per-node grids
    const int nodeBlocks = (N + 255) / 256;
    const int edgeBlocks = (E + 255) / 256;

    k_hist<<<edgeBlocks, 256, 0, stream>>>(src, dst, cnt, N, E);
    k_scan1<<<NB, 256, 0, stream>>>(cnt, bsum, n2);
    k_scan2<<<1, 1024, 0, stream>>>(bsum, NB);
    k_scan3<<<NB, 256, 0, stream>>>(cnt, bsum, off, cur, dinv, N, n2, (unsigned)(2 * E));
    k_scatter<<<edgeBlocks, 256, 0, stream>>>(src, dst, cur, pay, N, E);
    k_gemm<<<(N + TN - 1) / TN, 256, 0, stream>>>(x, W, dinv, h0s, N);
    k_agg<<<nodeW, 256, 0, stream>>>(off, pay, dinv, h0s, b, h, N);
    k_energy<<<nodeW, 256, 0, stream>>>(off, pay, h, e, S, N);
    k_max<<<400, 256, 0, stream>>>(e, Tptr, maxenc, N);
    k_sums<<<400, 256, 0, stream>>>(e, Tptr, maxenc, Zp, Mp, N);
    k_coef<<<nodeBlocks, 256, 0, stream>>>(e, Tptr, maxenc, Zp, Mp, c, N);
    k_grad_final<<<nodeW, 256, 0, stream>>>(off, pay, c, h, S, cnt, wptr, out, N);
}

// Round 4
// 522.246 us; speedup vs baseline: 2.2411x; 1.1494x over previous
//
#include <hip/hip_runtime.h>

#define DIN  128
#define DOUT 64
#define TN   64    // nodes per gemm block
#define XP   132   // padded X-tile row (floats)
#define NPHASE 8   // scatter phases (dst/src octiles)
#define NSTATB 400 // stat partial blocks

// ---------- K1: histogram in-degree (cnt[0..N)) and out-degree (cnt[N..2N)) ----------
__global__ __launch_bounds__(256) void k_hist(const int* __restrict__ src,
                                              const int* __restrict__ dst,
                                              unsigned* __restrict__ cnt,
                                              int N, int E) {
    int i = blockIdx.x * 256 + threadIdx.x;
    if (i < E) {
        atomicAdd(&cnt[dst[i]], 1u);
        atomicAdd(&cnt[N + src[i]], 1u);
    }
}

// ---------- K2: per-block reduce for scan ----------
__global__ __launch_bounds__(256) void k_scan1(const unsigned* __restrict__ cnt,
                                               unsigned* __restrict__ bsums, int n2) {
    __shared__ unsigned s[256];
    int i = blockIdx.x * 256 + threadIdx.x;
    s[threadIdx.x] = (i < n2) ? cnt[i] : 0u;
    __syncthreads();
    for (int st = 128; st > 0; st >>= 1) {
        if (threadIdx.x < st) s[threadIdx.x] += s[threadIdx.x + st];
        __syncthreads();
    }
    if (threadIdx.x == 0) bsums[blockIdx.x] = s[0];
}

// ---------- K3: single-block exclusive scan of block sums (NB <= 1024) ----------
__global__ __launch_bounds__(1024) void k_scan2(unsigned* __restrict__ bsums, int NB) {
    __shared__ unsigned s[1024];
    int tid = threadIdx.x;
    unsigned v = (tid < NB) ? bsums[tid] : 0u;
    s[tid] = v;
    __syncthreads();
    for (int st = 1; st < 1024; st <<= 1) {
        unsigned t = (tid >= st) ? s[tid - st] : 0u;
        __syncthreads();
        s[tid] += t;
        __syncthreads();
    }
    if (tid < NB) bsums[tid] = s[tid] - v;   // exclusive
}

// ---------- K4: block scan + add base -> off, cur; also dinv ----------
__global__ __launch_bounds__(256) void k_scan3(const unsigned* __restrict__ cnt,
                                               const unsigned* __restrict__ bsums,
                                               unsigned* __restrict__ off,
                                               unsigned* __restrict__ cur,
                                               float* __restrict__ dinv,
                                               int N, int n2, unsigned total) {
    __shared__ unsigned s[256];
    int i = blockIdx.x * 256 + threadIdx.x;
    unsigned v = (i < n2) ? cnt[i] : 0u;
    s[threadIdx.x] = v;
    __syncthreads();
    for (int st = 1; st < 256; st <<= 1) {
        unsigned t = (threadIdx.x >= st) ? s[threadIdx.x - st] : 0u;
        __syncthreads();
        s[threadIdx.x] += t;
        __syncthreads();
    }
    unsigned excl = s[threadIdx.x] - v + bsums[blockIdx.x];
    if (i < n2) {
        off[i] = excl;
        cur[i] = excl;
        if (i < N) dinv[i] = rsqrtf((float)v + 1.f);
    }
    if (i == 0) off[n2] = total;
}

// ---------- K5: phased scatter of edge payloads into both CSRs ----------
// Phase p (blockIdx.x / nEB) only writes payloads whose TARGET node is in
// octile p, so the write region per phase (~1 MB) stays L2-resident and
// lines fill before writeback. Relies on dispatch order only for SPEED.
__global__ __launch_bounds__(256) void k_scatter(const int* __restrict__ src,
                                                 const int* __restrict__ dst,
                                                 unsigned* __restrict__ cur,
                                                 int* __restrict__ pay,
                                                 int N, int E, int nEB, int bound) {
    int phase = blockIdx.x / nEB;
    int i = (blockIdx.x - phase * nEB) * 256 + threadIdx.x;
    if (i >= E) return;
    int lo = phase * bound;
    int hi = lo + bound;
    int s = src[i], d = dst[i];
    if (d >= lo && d < hi) {
        unsigned p1 = atomicAdd(&cur[d], 1u);
        pay[p1] = s;                       // in-CSR stores src id
    }
    if (s >= lo && s < hi) {
        unsigned p2 = atomicAdd(&cur[N + s], 1u);
        pay[p2] = d;                       // out-CSR stores dst id
    }
}

// ---------- K6: h0s = dinv[n] * (x[n] @ W)  register-blocked 4x4 tile GEMM ----------
__global__ __launch_bounds__(256) void k_gemm(const float* __restrict__ x,
                                              const float* __restrict__ W,
                                              const float* __restrict__ dinv,
                                              float* __restrict__ h0s, int N) {
    __shared__ float Xs[TN * XP];
    __shared__ float Ws[DIN * DOUT];

    for (int i = threadIdx.x; i < DIN * DOUT / 4; i += 256)
        ((float4*)Ws)[i] = ((const float4*)W)[i];

    int base = blockIdx.x * TN;
    int kq = threadIdx.x & 31;
    int rr = threadIdx.x >> 5;
#pragma unroll
    for (int it = 0; it < 8; ++it) {
        int r = rr + it * 8;
        int n = base + r;
        float4 v = make_float4(0.f, 0.f, 0.f, 0.f);
        if (n < N) v = ((const float4*)(x + (size_t)n * DIN))[kq];
        *((float4*)(Xs + r * XP + 4 * kq)) = v;
    }
    __syncthreads();

    int tx = threadIdx.x & 15;
    int ty = threadIdx.x >> 4;
    float acc[4][4] = {};

#pragma unroll 4
    for (int k = 0; k < DIN; k += 4) {
        float4 a0 = *((float4*)(Xs + (4 * ty + 0) * XP + k));
        float4 a1 = *((float4*)(Xs + (4 * ty + 1) * XP + k));
        float4 a2 = *((float4*)(Xs + (4 * ty + 2) * XP + k));
        float4 a3 = *((float4*)(Xs + (4 * ty + 3) * XP + k));
        float4 w0 = *((float4*)(Ws + (k + 0) * DOUT + 4 * tx));
        float4 w1 = *((float4*)(Ws + (k + 1) * DOUT + 4 * tx));
        float4 w2 = *((float4*)(Ws + (k + 2) * DOUT + 4 * tx));
        float4 w3 = *((float4*)(Ws + (k + 3) * DOUT + 4 * tx));
#define ROW(j, aj)                                                             \
        acc[j][0] = fmaf(aj.x, w0.x, fmaf(aj.y, w1.x, fmaf(aj.z, w2.x, fmaf(aj.w, w3.x, acc[j][0])))); \
        acc[j][1] = fmaf(aj.x, w0.y, fmaf(aj.y, w1.y, fmaf(aj.z, w2.y, fmaf(aj.w, w3.y, acc[j][1])))); \
        acc[j][2] = fmaf(aj.x, w0.z, fmaf(aj.y, w1.z, fmaf(aj.z, w2.z, fmaf(aj.w, w3.z, acc[j][2])))); \
        acc[j][3] = fmaf(aj.x, w0.w, fmaf(aj.y, w1.w, fmaf(aj.z, w2.w, fmaf(aj.w, w3.w, acc[j][3]))));
        ROW(0, a0) ROW(1, a1) ROW(2, a2) ROW(3, a3)
#undef ROW
    }

#pragma unroll
    for (int j = 0; j < 4; ++j) {
        int n = base + 4 * ty + j;
        if (n < N) {
            float dv = dinv[n];
            float4 o = make_float4(acc[j][0] * dv, acc[j][1] * dv,
                                   acc[j][2] * dv, acc[j][3] * dv);
            *((float4*)(h0s + (size_t)n * DOUT + 4 * tx)) = o;
        }
    }
}

// ---------- K7: gather agg + fused combine ----------
__global__ __launch_bounds__(256) void k_agg(const unsigned* __restrict__ off,
                                             const int* __restrict__ pay,
                                             const float* __restrict__ dinv,
                                             const float* __restrict__ h0s,
                                             const float* __restrict__ b,
                                             float* __restrict__ h, int N) {
    int wave = threadIdx.x >> 6;
    int lane = threadIdx.x & 63;
    int n = blockIdx.x * 4 + wave;
    if (n >= N) return;
    int beg = off[n], end = off[n + 1];
    float acc = 0.f;
    int i = beg;
    for (; i + 2 <= end; i += 2) {
        int s0 = pay[i], s1 = pay[i + 1];
        float a0 = h0s[(size_t)s0 * DOUT + lane];
        float a1 = h0s[(size_t)s1 * DOUT + lane];
        acc += a0 + a1;
    }
    if (i < end) acc += h0s[(size_t)pay[i] * DOUT + lane];
    h[(size_t)n * DOUT + lane] = dinv[n] * (acc + h0s[(size_t)n * DOUT + lane]) + b[lane];
}

// ---------- K8: gather energy + S ----------
__global__ __launch_bounds__(256) void k_energy(const unsigned* __restrict__ off,
                                                const int* __restrict__ pay,
                                                const float* __restrict__ h,
                                                float* __restrict__ e,
                                                float* __restrict__ S, int N) {
    int wave = threadIdx.x >> 6;
    int lane = threadIdx.x & 63;
    int n = blockIdx.x * 4 + wave;
    if (n >= N) return;
    int beg = off[n], end = off[n + 1];
    float hm = h[(size_t)n * DOUT + lane];
    float Ssum = 0.f, esum = 0.f;
    int i = beg;
    for (; i + 2 <= end; i += 2) {
        int s0 = pay[i], s1 = pay[i + 1];
        float h0v = h[(size_t)s0 * DOUT + lane];
        float h1v = h[(size_t)s1 * DOUT + lane];
        Ssum += h0v + h1v;
        float d0 = hm - h0v, d1 = hm - h1v;
        esum += d0 * d0 + d1 * d1;
    }
    if (i < end) {
        float hv = h[(size_t)pay[i] * DOUT + lane];
        Ssum += hv;
        float d = hm - hv;
        esum += d * d;
    }
#pragma unroll
    for (int o = 32; o > 0; o >>= 1) esum += __shfl_down(esum, o, 64);
    if (lane == 0) e[n] = esum;
    S[(size_t)n * DOUT + lane] = Ssum;
}

// ---------- K9: per-block softmax partials (m, Z, M) ----------
__global__ __launch_bounds__(256) void k_stats1(const float* __restrict__ e,
                                                const float* __restrict__ Tptr,
                                                float* __restrict__ part, int N) {
    float T = *Tptr;
    float m = -3.4e38f;
    int i0 = blockIdx.x * 256 + threadIdx.x;
    int stride = gridDim.x * 256;
    for (int i = i0; i < N; i += stride) m = fmaxf(m, -e[i] / T);
    __shared__ float sm[256];
    sm[threadIdx.x] = m;
    __syncthreads();
    for (int s = 128; s > 0; s >>= 1) {
        if (threadIdx.x < s) sm[threadIdx.x] = fmaxf(sm[threadIdx.x], sm[threadIdx.x + s]);
        __syncthreads();
    }
    float bm = sm[0];
    __syncthreads();
    float z = 0.f, mm = 0.f;
    for (int i = i0; i < N; i += stride) {
        float t = -e[i] / T - bm;
        float w = __expf(t);
        z += w;
        mm += w * t;
    }
    __shared__ float sz[256], sM[256];
    sz[threadIdx.x] = z;
    sM[threadIdx.x] = mm;
    __syncthreads();
    for (int s = 128; s > 0; s >>= 1) {
        if (threadIdx.x < s) {
            sz[threadIdx.x] += sz[threadIdx.x + s];
            sM[threadIdx.x] += sM[threadIdx.x + s];
        }
        __syncthreads();
    }
    if (threadIdx.x == 0) {
        part[blockIdx.x * 3 + 0] = bm;
        part[blockIdx.x * 3 + 1] = sz[0];
        part[blockIdx.x * 3 + 2] = sM[0];
    }
}

// ---------- K10: merge partials with rescaling -> st = {m, Z, M} ----------
__global__ __launch_bounds__(256) void k_stats2(const float* __restrict__ part,
                                                float* __restrict__ st, int P) {
    __shared__ float sm[256];
    float m = -3.4e38f;
    for (int i = threadIdx.x; i < P; i += 256) m = fmaxf(m, part[3 * i]);
    sm[threadIdx.x] = m;
    __syncthreads();
    for (int s = 128; s > 0; s >>= 1) {
        if (threadIdx.x < s) sm[threadIdx.x] = fmaxf(sm[threadIdx.x], sm[threadIdx.x + s]);
        __syncthreads();
    }
    float gm = sm[0];
    __syncthreads();
    float Z = 0.f, M = 0.f;
    for (int i = threadIdx.x; i < P; i += 256) {
        float mb = part[3 * i], zb = part[3 * i + 1], Mb = part[3 * i + 2];
        float d = mb - gm, eb = __expf(d);
        Z += eb * zb;
        M += eb * (Mb + d * zb);
    }
    __shared__ float sz[256], sM2[256];
    sz[threadIdx.x] = Z;
    sM2[threadIdx.x] = M;
    __syncthreads();
    for (int s = 128; s > 0; s >>= 1) {
        if (threadIdx.x < s) {
            sz[threadIdx.x] += sz[threadIdx.x + s];
            sM2[threadIdx.x] += sM2[threadIdx.x + s];
        }
        __syncthreads();
    }
    if (threadIdx.x == 0) {
        st[0] = gm;
        st[1] = sz[0];
        st[2] = sM2[0];
    }
}

// ---------- K11: c_n = p_n * (logp_n + H) ----------
__global__ __launch_bounds__(256) void k_coef(const float* __restrict__ e,
                                              const float* __restrict__ Tptr,
                                              const float* __restrict__ st,
                                              float* __restrict__ c, int N) {
    int n = blockIdx.x * 256 + threadIdx.x;
    if (n >= N) return;
    float T = *Tptr;
    float gm = st[0], Z = st[1], M = st[2];
    float logZ = logf(Z);
    float H = logZ - M / Z;
    float t = -e[n] / T - gm;
    float lp = t - logZ;
    c[n] = expf(lp) * (lp + H);
}

// ---------- K12: out-CSR gather of A,B + fused final ----------
__global__ __launch_bounds__(256) void k_grad_final(const unsigned* __restrict__ off,
                                                    const int* __restrict__ pay,
                                                    const float* __restrict__ c,
                                                    const float* __restrict__ h,
                                                    const float* __restrict__ S,
                                                    const unsigned* __restrict__ cnt,
                                                    const float* __restrict__ wptr,
                                                    float* __restrict__ out, int N) {
    int wave = threadIdx.x >> 6;
    int lane = threadIdx.x & 63;
    int n = blockIdx.x * 4 + wave;
    if (n >= N) return;
    int beg = off[N + n], end = off[N + n + 1];
    float A = 0.f, B = 0.f;
    int i = beg;
    for (; i + 2 <= end; i += 2) {
        int d0 = pay[i], d1 = pay[i + 1];
        float c0 = c[d0], c1 = c[d1];
        B += c0 * h[(size_t)d0 * DOUT + lane] + c1 * h[(size_t)d1 * DOUT + lane];
        A += c0 + c1;
    }
    if (i < end) {
        int d = pay[i];
        float cd = c[d];
        B += cd * h[(size_t)d * DOUT + lane];
        A += cd;
    }
    size_t idx = (size_t)n * DOUT + lane;
    float hm = h[idx];
    float w = *wptr;
    float g = 2.f * c[n] * ((float)cnt[n] * hm - S[idx]) + 2.f * (A * hm - B);
    out[idx] = hm + w * g;
}

extern "C" void kernel_launch(void* const* d_in, const int* in_sizes, int n_in,
                              void* d_out, int out_size, void* d_ws, size_t ws_size,
                              hipStream_t stream) {
    const float* x    = (const float*)d_in[0];
    const int*   ei   = (const int*)d_in[1];
    const float* wptr = (const float*)d_in[2];
    const float* Tptr = (const float*)d_in[3];
    const float* W    = (const float*)d_in[4];
    const float* b    = (const float*)d_in[5];
    float* out = (float*)d_out;

    const int N  = in_sizes[0] / DIN;   // 100000
    const int E  = in_sizes[1] / 2;     // 1000000
    const int NE = N * DOUT;
    const int n2 = 2 * N;
    const int NB = (n2 + 255) / 256;
    const int* src = ei;
    const int* dst = ei + E;

    // workspace layout
    float*    h0s  = (float*)d_ws;                 // NE (reused as S later)
    float*    h    = h0s + NE;                     // NE
    int*      pay  = (int*)(h + NE);               // 2E
    unsigned* cnt  = (unsigned*)(pay + 2 * (size_t)E);  // 2N
    unsigned* off  = cnt + n2;                     // 2N+1
    unsigned* cur  = off + n2 + 1;                 // 2N
    unsigned* bsum = cur + n2;                     // NB (<=1024)
    float*    e    = (float*)(bsum + 1024);        // N
    float*    c    = e + N;                        // N
    float*    dinv = c + N;                        // N
    float*    part = dinv + N;                     // 3*NSTATB
    float*    st   = part + 3 * NSTATB;            // 3
    float*    S    = h0s;                          // reuse after k_agg

    hipMemsetAsync(cnt, 0, (size_t)n2 * 4, stream);

    const int nodeW = (N + 3) / 4;
    const int nodeBlocks = (N + 255) / 256;
    const int edgeBlocks = (E + 255) / 256;
    const int bound = (N + NPHASE - 1) / NPHASE;

    k_hist<<<edgeBlocks, 256, 0, stream>>>(src, dst, cnt, N, E);
    k_scan1<<<NB, 256, 0, stream>>>(cnt, bsum, n2);
    k_scan2<<<1, 1024, 0, stream>>>(bsum, NB);
    k_scan3<<<NB, 256, 0, stream>>>(cnt, bsum, off, cur, dinv, N, n2, (unsigned)(2 * E));
    k_scatter<<<NPHASE * edgeBlocks, 256, 0, stream>>>(src, dst, cur, pay, N, E, edgeBlocks, bound);
    k_gemm<<<(N + TN - 1) / TN, 256, 0, stream>>>(x, W, dinv, h0s, N);
    k_agg<<<nodeW, 256, 0, stream>>>(off, pay, dinv, h0s, b, h, N);
    k_energy<<<nodeW, 256, 0, stream>>>(off, pay, h, e, S, N);
    k_stats1<<<NSTATB, 256, 0, stream>>>(e, Tptr, part, N);
    k_stats2<<<1, 256, 0, stream>>>(part, st, NSTATB);
    k_coef<<<nodeBlocks, 256, 0, stream>>>(e, Tptr, st, c, N);
    k_grad_final<<<nodeW, 256, 0, stream>>>(off, pay, c, h, S, cnt, wptr, out, N);
}

// Round 5
// 514.402 us; speedup vs baseline: 2.2752x; 1.0153x over previous
//
#include <hip/hip_runtime.h>

#define DIN  128
#define DOUT 64
#define TN   64    // nodes per gemm block
#define XP   132   // padded X-tile row (floats)
#define NPHASE 8   // = #XCDs; phase p owned by XCD p via blockIdx&7 round-robin
#define SCB  256   // blocks per phase for phased edge kernels
#define NSTATB 400 // stat partial blocks

// ---------- K1: phased histogram — in-degree cnt[0..N), out-degree cnt[N..2N)
// phase = blockIdx&7 -> one XCD owns one node-octile's counters (L2-local atomics).
__global__ __launch_bounds__(256) void k_hist(const int* __restrict__ src,
                                              const int* __restrict__ dst,
                                              unsigned* __restrict__ cnt,
                                              int N, int E, int bound) {
    int phase = blockIdx.x & (NPHASE - 1);
    int blk   = blockIdx.x >> 3;
    int lo = phase * bound, hi = lo + bound;
    for (int i = blk * 256 + threadIdx.x; i < E; i += SCB * 256) {
        int d = dst[i], s = src[i];
        if (d >= lo && d < hi) atomicAdd(&cnt[d], 1u);
        if (s >= lo && s < hi) atomicAdd(&cnt[N + s], 1u);
    }
}

// ---------- K2: per-block reduce for scan ----------
__global__ __launch_bounds__(256) void k_scan1(const unsigned* __restrict__ cnt,
                                               unsigned* __restrict__ bsums, int n2) {
    __shared__ unsigned s[256];
    int i = blockIdx.x * 256 + threadIdx.x;
    s[threadIdx.x] = (i < n2) ? cnt[i] : 0u;
    __syncthreads();
    for (int st = 128; st > 0; st >>= 1) {
        if (threadIdx.x < st) s[threadIdx.x] += s[threadIdx.x + st];
        __syncthreads();
    }
    if (threadIdx.x == 0) bsums[blockIdx.x] = s[0];
}

// ---------- K3: single-block exclusive scan of block sums (NB <= 1024) ----------
__global__ __launch_bounds__(1024) void k_scan2(unsigned* __restrict__ bsums, int NB) {
    __shared__ unsigned s[1024];
    int tid = threadIdx.x;
    unsigned v = (tid < NB) ? bsums[tid] : 0u;
    s[tid] = v;
    __syncthreads();
    for (int st = 1; st < 1024; st <<= 1) {
        unsigned t = (tid >= st) ? s[tid - st] : 0u;
        __syncthreads();
        s[tid] += t;
        __syncthreads();
    }
    if (tid < NB) bsums[tid] = s[tid] - v;   // exclusive
}

// ---------- K4: block scan + add base -> off, cur; also dinv ----------
__global__ __launch_bounds__(256) void k_scan3(const unsigned* __restrict__ cnt,
                                               const unsigned* __restrict__ bsums,
                                               unsigned* __restrict__ off,
                                               unsigned* __restrict__ cur,
                                               float* __restrict__ dinv,
                                               int N, int n2, unsigned total) {
    __shared__ unsigned s[256];
    int i = blockIdx.x * 256 + threadIdx.x;
    unsigned v = (i < n2) ? cnt[i] : 0u;
    s[threadIdx.x] = v;
    __syncthreads();
    for (int st = 1; st < 256; st <<= 1) {
        unsigned t = (threadIdx.x >= st) ? s[threadIdx.x - st] : 0u;
        __syncthreads();
        s[threadIdx.x] += t;
        __syncthreads();
    }
    unsigned excl = s[threadIdx.x] - v + bsums[blockIdx.x];
    if (i < n2) {
        off[i] = excl;
        cur[i] = excl;
        if (i < N) dinv[i] = rsqrtf((float)v + 1.f);
    }
    if (i == 0) off[n2] = total;
}

// ---------- K5: phased scatter, XCD-owned octiles (same mapping as k_hist) ----------
__global__ __launch_bounds__(256) void k_scatter(const int* __restrict__ src,
                                                 const int* __restrict__ dst,
                                                 unsigned* __restrict__ cur,
                                                 int* __restrict__ pay,
                                                 int N, int E, int bound) {
    int phase = blockIdx.x & (NPHASE - 1);
    int blk   = blockIdx.x >> 3;
    int lo = phase * bound, hi = lo + bound;
    for (int i = blk * 256 + threadIdx.x; i < E; i += SCB * 256) {
        int s = src[i], d = dst[i];
        if (d >= lo && d < hi) {
            unsigned p1 = atomicAdd(&cur[d], 1u);
            pay[p1] = s;                       // in-CSR stores src id
        }
        if (s >= lo && s < hi) {
            unsigned p2 = atomicAdd(&cur[N + s], 1u);
            pay[p2] = d;                       // out-CSR stores dst id
        }
    }
}

// ---------- K6: h0s = dinv[n] * (x[n] @ W)  register-blocked 4x4 tile GEMM ----------
__global__ __launch_bounds__(256) void k_gemm(const float* __restrict__ x,
                                              const float* __restrict__ W,
                                              const float* __restrict__ dinv,
                                              float* __restrict__ h0s, int N) {
    __shared__ float Xs[TN * XP];
    __shared__ float Ws[DIN * DOUT];

    for (int i = threadIdx.x; i < DIN * DOUT / 4; i += 256)
        ((float4*)Ws)[i] = ((const float4*)W)[i];

    int base = blockIdx.x * TN;
    int kq = threadIdx.x & 31;
    int rr = threadIdx.x >> 5;
#pragma unroll
    for (int it = 0; it < 8; ++it) {
        int r = rr + it * 8;
        int n = base + r;
        float4 v = make_float4(0.f, 0.f, 0.f, 0.f);
        if (n < N) v = ((const float4*)(x + (size_t)n * DIN))[kq];
        *((float4*)(Xs + r * XP + 4 * kq)) = v;
    }
    __syncthreads();

    int tx = threadIdx.x & 15;
    int ty = threadIdx.x >> 4;
    float acc[4][4] = {};

#pragma unroll 4
    for (int k = 0; k < DIN; k += 4) {
        float4 a0 = *((float4*)(Xs + (4 * ty + 0) * XP + k));
        float4 a1 = *((float4*)(Xs + (4 * ty + 1) * XP + k));
        float4 a2 = *((float4*)(Xs + (4 * ty + 2) * XP + k));
        float4 a3 = *((float4*)(Xs + (4 * ty + 3) * XP + k));
        float4 w0 = *((float4*)(Ws + (k + 0) * DOUT + 4 * tx));
        float4 w1 = *((float4*)(Ws + (k + 1) * DOUT + 4 * tx));
        float4 w2 = *((float4*)(Ws + (k + 2) * DOUT + 4 * tx));
        float4 w3 = *((float4*)(Ws + (k + 3) * DOUT + 4 * tx));
#define ROW(j, aj)                                                             \
        acc[j][0] = fmaf(aj.x, w0.x, fmaf(aj.y, w1.x, fmaf(aj.z, w2.x, fmaf(aj.w, w3.x, acc[j][0])))); \
        acc[j][1] = fmaf(aj.x, w0.y, fmaf(aj.y, w1.y, fmaf(aj.z, w2.y, fmaf(aj.w, w3.y, acc[j][1])))); \
        acc[j][2] = fmaf(aj.x, w0.z, fmaf(aj.y, w1.z, fmaf(aj.z, w2.z, fmaf(aj.w, w3.z, acc[j][2])))); \
        acc[j][3] = fmaf(aj.x, w0.w, fmaf(aj.y, w1.w, fmaf(aj.z, w2.w, fmaf(aj.w, w3.w, acc[j][3]))));
        ROW(0, a0) ROW(1, a1) ROW(2, a2) ROW(3, a3)
#undef ROW
    }

#pragma unroll
    for (int j = 0; j < 4; ++j) {
        int n = base + 4 * ty + j;
        if (n < N) {
            float dv = dinv[n];
            float4 o = make_float4(acc[j][0] * dv, acc[j][1] * dv,
                                   acc[j][2] * dv, acc[j][3] * dv);
            *((float4*)(h0s + (size_t)n * DOUT + 4 * tx)) = o;
        }
    }
}

// ---------- K7: gather agg + fused combine ----------
__global__ __launch_bounds__(256) void k_agg(const unsigned* __restrict__ off,
                                             const int* __restrict__ pay,
                                             const float* __restrict__ dinv,
                                             const float* __restrict__ h0s,
                                             const float* __restrict__ b,
                                             float* __restrict__ h, int N) {
    int wave = threadIdx.x >> 6;
    int lane = threadIdx.x & 63;
    int n = blockIdx.x * 4 + wave;
    if (n >= N) return;
    int beg = off[n], end = off[n + 1];
    float acc = 0.f;
    int i = beg;
    for (; i + 2 <= end; i += 2) {
        int s0 = pay[i], s1 = pay[i + 1];
        float a0 = h0s[(size_t)s0 * DOUT + lane];
        float a1 = h0s[(size_t)s1 * DOUT + lane];
        acc += a0 + a1;
    }
    if (i < end) acc += h0s[(size_t)pay[i] * DOUT + lane];
    h[(size_t)n * DOUT + lane] = dinv[n] * (acc + h0s[(size_t)n * DOUT + lane]) + b[lane];
}

// ---------- K8: gather energy + S ----------
__global__ __launch_bounds__(256) void k_energy(const unsigned* __restrict__ off,
                                                const int* __restrict__ pay,
                                                const float* __restrict__ h,
                                                float* __restrict__ e,
                                                float* __restrict__ S, int N) {
    int wave = threadIdx.x >> 6;
    int lane = threadIdx.x & 63;
    int n = blockIdx.x * 4 + wave;
    if (n >= N) return;
    int beg = off[n], end = off[n + 1];
    float hm = h[(size_t)n * DOUT + lane];
    float Ssum = 0.f, esum = 0.f;
    int i = beg;
    for (; i + 2 <= end; i += 2) {
        int s0 = pay[i], s1 = pay[i + 1];
        float h0v = h[(size_t)s0 * DOUT + lane];
        float h1v = h[(size_t)s1 * DOUT + lane];
        Ssum += h0v + h1v;
        float d0 = hm - h0v, d1 = hm - h1v;
        esum += d0 * d0 + d1 * d1;
    }
    if (i < end) {
        float hv = h[(size_t)pay[i] * DOUT + lane];
        Ssum += hv;
        float d = hm - hv;
        esum += d * d;
    }
#pragma unroll
    for (int o = 32; o > 0; o >>= 1) esum += __shfl_down(esum, o, 64);
    if (lane == 0) e[n] = esum;
    S[(size_t)n * DOUT + lane] = Ssum;
}

// ---------- K9: per-block softmax partials (m, Z, M) ----------
__global__ __launch_bounds__(256) void k_stats1(const float* __restrict__ e,
                                                const float* __restrict__ Tptr,
                                                float* __restrict__ part, int N) {
    float T = *Tptr;
    float m = -3.4e38f;
    int i0 = blockIdx.x * 256 + threadIdx.x;
    int stride = gridDim.x * 256;
    for (int i = i0; i < N; i += stride) m = fmaxf(m, -e[i] / T);
    __shared__ float sm[256];
    sm[threadIdx.x] = m;
    __syncthreads();
    for (int s = 128; s > 0; s >>= 1) {
        if (threadIdx.x < s) sm[threadIdx.x] = fmaxf(sm[threadIdx.x], sm[threadIdx.x + s]);
        __syncthreads();
    }
    float bm = sm[0];
    __syncthreads();
    float z = 0.f, mm = 0.f;
    for (int i = i0; i < N; i += stride) {
        float t = -e[i] / T - bm;
        float w = __expf(t);
        z += w;
        mm += w * t;
    }
    __shared__ float sz[256], sM[256];
    sz[threadIdx.x] = z;
    sM[threadIdx.x] = mm;
    __syncthreads();
    for (int s = 128; s > 0; s >>= 1) {
        if (threadIdx.x < s) {
            sz[threadIdx.x] += sz[threadIdx.x + s];
            sM[threadIdx.x] += sM[threadIdx.x + s];
        }
        __syncthreads();
    }
    if (threadIdx.x == 0) {
        part[blockIdx.x * 3 + 0] = bm;
        part[blockIdx.x * 3 + 1] = sz[0];
        part[blockIdx.x * 3 + 2] = sM[0];
    }
}

// ---------- K10: merge partials with rescaling -> st = {m, Z, M} ----------
__global__ __launch_bounds__(256) void k_stats2(const float* __restrict__ part,
                                                float* __restrict__ st, int P) {
    __shared__ float sm[256];
    float m = -3.4e38f;
    for (int i = threadIdx.x; i < P; i += 256) m = fmaxf(m, part[3 * i]);
    sm[threadIdx.x] = m;
    __syncthreads();
    for (int s = 128; s > 0; s >>= 1) {
        if (threadIdx.x < s) sm[threadIdx.x] = fmaxf(sm[threadIdx.x], sm[threadIdx.x + s]);
        __syncthreads();
    }
    float gm = sm[0];
    __syncthreads();
    float Z = 0.f, M = 0.f;
    for (int i = threadIdx.x; i < P; i += 256) {
        float mb = part[3 * i], zb = part[3 * i + 1], Mb = part[3 * i + 2];
        float d = mb - gm, eb = __expf(d);
        Z += eb * zb;
        M += eb * (Mb + d * zb);
    }
    __shared__ float sz[256], sM2[256];
    sz[threadIdx.x] = Z;
    sM2[threadIdx.x] = M;
    __syncthreads();
    for (int s = 128; s > 0; s >>= 1) {
        if (threadIdx.x < s) {
            sz[threadIdx.x] += sz[threadIdx.x + s];
            sM2[threadIdx.x] += sM2[threadIdx.x + s];
        }
        __syncthreads();
    }
    if (threadIdx.x == 0) {
        st[0] = gm;
        st[1] = sz[0];
        st[2] = sM2[0];
    }
}

// ---------- K11: c_n = p_n * (logp_n + H) ----------
__global__ __launch_bounds__(256) void k_coef(const float* __restrict__ e,
                                              const float* __restrict__ Tptr,
                                              const float* __restrict__ st,
                                              float* __restrict__ c, int N) {
    int n = blockIdx.x * 256 + threadIdx.x;
    if (n >= N) return;
    float T = *Tptr;
    float gm = st[0], Z = st[1], M = st[2];
    float logZ = logf(Z);
    float H = logZ - M / Z;
    float t = -e[n] / T - gm;
    float lp = t - logZ;
    c[n] = expf(lp) * (lp + H);
}

// ---------- K12: out-CSR gather of A,B + fused final ----------
__global__ __launch_bounds__(256) void k_grad_final(const unsigned* __restrict__ off,
                                                    const int* __restrict__ pay,
                                                    const float* __restrict__ c,
                                                    const float* __restrict__ h,
                                                    const float* __restrict__ S,
                                                    const unsigned* __restrict__ cnt,
                                                    const float* __restrict__ wptr,
                                                    float* __restrict__ out, int N) {
    int wave = threadIdx.x >> 6;
    int lane = threadIdx.x & 63;
    int n = blockIdx.x * 4 + wave;
    if (n >= N) return;
    int beg = off[N + n], end = off[N + n + 1];
    float A = 0.f, B = 0.f;
    int i = beg;
    for (; i + 2 <= end; i += 2) {
        int d0 = pay[i], d1 = pay[i + 1];
        float c0 = c[d0], c1 = c[d1];
        B += c0 * h[(size_t)d0 * DOUT + lane] + c1 * h[(size_t)d1 * DOUT + lane];
        A += c0 + c1;
    }
    if (i < end) {
        int d = pay[i];
        float cd = c[d];
        B += cd * h[(size_t)d * DOUT + lane];
        A += cd;
    }
    size_t idx = (size_t)n * DOUT + lane;
    float hm = h[idx];
    float w = *wptr;
    float g = 2.f * c[n] * ((float)cnt[n] * hm - S[idx]) + 2.f * (A * hm - B);
    out[idx] = hm + w * g;
}

extern "C" void kernel_launch(void* const* d_in, const int* in_sizes, int n_in,
                              void* d_out, int out_size, void* d_ws, size_t ws_size,
                              hipStream_t stream) {
    const float* x    = (const float*)d_in[0];
    const int*   ei   = (const int*)d_in[1];
    const float* wptr = (const float*)d_in[2];
    const float* Tptr = (const float*)d_in[3];
    const float* W    = (const float*)d_in[4];
    const float* b    = (const float*)d_in[5];
    float* out = (float*)d_out;

    const int N  = in_sizes[0] / DIN;   // 100000
    const int E  = in_sizes[1] / 2;     // 1000000
    const int NE = N * DOUT;
    const int n2 = 2 * N;
    const int NB = (n2 + 255) / 256;
    const int* src = ei;
    const int* dst = ei + E;

    // workspace layout
    float*    h0s  = (float*)d_ws;                 // NE (reused as S later)
    float*    h    = h0s + NE;                     // NE
    int*      pay  = (int*)(h + NE);               // 2E
    unsigned* cnt  = (unsigned*)(pay + 2 * (size_t)E);  // 2N
    unsigned* off  = cnt + n2;                     // 2N+1
    unsigned* cur  = off + n2 + 1;                 // 2N
    unsigned* bsum = cur + n2;                     // NB (<=1024)
    float*    e    = (float*)(bsum + 1024);        // N
    float*    c    = e + N;                        // N
    float*    dinv = c + N;                        // N
    float*    part = dinv + N;                     // 3*NSTATB
    float*    st   = part + 3 * NSTATB;            // 3
    float*    S    = h0s;                          // reuse after k_agg

    hipMemsetAsync(cnt, 0, (size_t)n2 * 4, stream);

    const int nodeW = (N + 3) / 4;
    const int nodeBlocks = (N + 255) / 256;
    const int bound = (N + NPHASE - 1) / NPHASE;

    k_hist<<<NPHASE * SCB, 256, 0, stream>>>(src, dst, cnt, N, E, bound);
    k_scan1<<<NB, 256, 0, stream>>>(cnt, bsum, n2);
    k_scan2<<<1, 1024, 0, stream>>>(bsum, NB);
    k_scan3<<<NB, 256, 0, stream>>>(cnt, bsum, off, cur, dinv, N, n2, (unsigned)(2 * E));
    k_scatter<<<NPHASE * SCB, 256, 0, stream>>>(src, dst, cur, pay, N, E, bound);
    k_gemm<<<(N + TN - 1) / TN, 256, 0, stream>>>(x, W, dinv, h0s, N);
    k_agg<<<nodeW, 256, 0, stream>>>(off, pay, dinv, h0s, b, h, N);
    k_energy<<<nodeW, 256, 0, stream>>>(off, pay, h, e, S, N);
    k_stats1<<<NSTATB, 256, 0, stream>>>(e, Tptr, part, N);
    k_stats2<<<1, 256, 0, stream>>>(part, st, NSTATB);
    k_coef<<<nodeBlocks, 256, 0, stream>>>(e, Tptr, st, c, N);
    k_grad_final<<<nodeW, 256, 0, stream>>>(off, pay, c, h, S, cnt, wptr, out, N);
}